// Round 1
// 278.086 us; speedup vs baseline: 1.3006x; 1.3006x over previous
//
#include <hip/hip_runtime.h>
#include <cstdint>
#include <cstddef>

#define NQ 2048
#define NK 2048
#define DH 128
#define SCALEF 1.153f
#define KEEPF  0.7f

typedef _Float16 half8 __attribute__((ext_vector_type(8)));
typedef float  floatx4 __attribute__((ext_vector_type(4)));

// Module-global scratch (d_ws untouched): preconverted x2 only (mask is now
// computed in-kernel — the 8 MiB g_mask round-trip is gone).
__device__ __align__(16) _Float16 g_x2h[16 * 2048 * 128];    // 8 MiB [b][k][d] hi
__device__ __align__(16) _Float16 g_x2l[16 * 2048 * 128];    // 8 MiB [b][k][d] lo
__device__ __align__(16) _Float16 g_x2t[16 * 128 * 2048];    // 8 MiB [b][d][k] hi

// ---------------------------------------------------------------------------
// Threefry-2x32, 20 rounds, key (0,42) — PARTITIONABLE path (HW-VERIFIED R8):
// cipher input (x0,x1) = (0, i); draw = y0 ^ y1; keep iff draw < 0xB3333400.
// DO NOT TOUCH the stream. Rotates via v_alignbit (rotr(x, 32-r) == rotl r).
// ---------------------------------------------------------------------------
__device__ __forceinline__ unsigned rotl(unsigned x, int r) {
  return __builtin_amdgcn_alignbit(x, x, 32 - r);
}
__device__ __forceinline__ void tf_round(unsigned& x0, unsigned& x1, int r) {
  x0 += x1;
  x1 = rotl(x1, r);
  x1 ^= x0;
}
#define KEEP_THRESH 0xB3333400u

// One full eval: returns 1 iff element i is KEPT. Exact same stream as the
// old prep_mask (x0 starts at 0 => first-round add folds to a copy).
__device__ __forceinline__ unsigned tf_keep(unsigned i) {
  const unsigned ks1 = 42u, ks2 = 0x1BD11BDAu ^ 42u;
  unsigned x0 = 0u;                       // hi32(count)
  unsigned x1 = i + ks1;                  // lo32(count) + initial inject (ks0=0)
  tf_round(x0,x1,13); tf_round(x0,x1,15); tf_round(x0,x1,26); tf_round(x0,x1, 6);
  x0 += ks1;  x1 += ks2 + 1u;
  tf_round(x0,x1,17); tf_round(x0,x1,29); tf_round(x0,x1,16); tf_round(x0,x1,24);
  x0 += ks2;  x1 += 2u;
  tf_round(x0,x1,13); tf_round(x0,x1,15); tf_round(x0,x1,26); tf_round(x0,x1, 6);
  /*x0+=0*/   x1 += ks1 + 3u;
  tf_round(x0,x1,17); tf_round(x0,x1,29); tf_round(x0,x1,16); tf_round(x0,x1,24);
  x0 += ks1;  x1 += ks2 + 4u;
  tf_round(x0,x1,13); tf_round(x0,x1,15); tf_round(x0,x1,26); tf_round(x0,x1, 6);
  x0 += ks2;  x1 += 5u;
  return (unsigned)((x0 ^ x1) < KEEP_THRESH);   // fold y0^y1
}

// ---------------------------------------------------------------------------
// prep_conv: blocks [0,1024) x2 -> hi/lo f16 row-major; [1024,3072) x2 ->
// transposed hi f16. (threefry mask generation moved into attn_kernel)
// ---------------------------------------------------------------------------
__global__ __launch_bounds__(256) void prep_conv(const float* __restrict__ x2) {
  const int blk = blockIdx.x;
  const int tid = threadIdx.x;

  if (blk < 1024) {
    // row-major hi/lo: 1,048,576 float4 chunks, coalesced
    const int g = blk * 256 + tid;
    const float4* src = (const float4*)x2;
    #pragma unroll
    for (int t = 0; t < 4; ++t) {
      int i = g + t * 262144;
      float4 v = src[i];
      _Float16 h0 = (_Float16)v.x, h1 = (_Float16)v.y,
               h2 = (_Float16)v.z, h3 = (_Float16)v.w;
      union { _Float16 h[4]; uint2 u; } hh, ll;
      hh.h[0] = h0; hh.h[1] = h1; hh.h[2] = h2; hh.h[3] = h3;
      ll.h[0] = (_Float16)(v.x - (float)h0);
      ll.h[1] = (_Float16)(v.y - (float)h1);
      ll.h[2] = (_Float16)(v.z - (float)h2);
      ll.h[3] = (_Float16)(v.w - (float)h3);
      *(uint2*)&g_x2h[(size_t)i * 4] = hh.u;
      *(uint2*)&g_x2l[(size_t)i * 4] = ll.u;
    }

  } else {
    // transpose hi: g_x2t[b][d][k] = (f16) x2[b][k][d]
    const int idx = blk - 1024;     // 0..2047
    const int b   = idx >> 7;
    const int rem = idx & 127;
    const int d8  = rem >> 3;       // 16 d-groups of 8
    const int kt  = rem & 7;        // 8 k-tiles of 256
    const int k   = kt * 256 + tid;
    const float* src = x2 + ((size_t)(b * NK + k)) * DH + d8 * 8;
    float4 v0 = *(const float4*)src;
    float4 v1 = *(const float4*)(src + 4);
    _Float16 h[8] = { (_Float16)v0.x, (_Float16)v0.y, (_Float16)v0.z, (_Float16)v0.w,
                      (_Float16)v1.x, (_Float16)v1.y, (_Float16)v1.z, (_Float16)v1.w };
    #pragma unroll
    for (int j = 0; j < 8; ++j)
      g_x2t[((size_t)(b * DH + d8 * 8 + j)) * NK + k] = h[j];   // coalesced in k
  }
}

// ---------------------------------------------------------------------------
// MFMA flash attention + FUSED threefry dropout. fp32 in / fp32 out.
// All staging is b128 copies from preconverted f16 with 16B-granule XOR
// swizzles (write & read sides consistent):
//   Ksh/Ksl: addr = r*128 + ((c8 ^ (r&15))<<3), r=kv-local row, c8=d-chunk
//   Vt:      addr = d*64  + ((ch ^ (d&7 ))<<3), ch=kv-chunk
// MFMA f16 16x16x32 layouts (m89/m120): A[m=lane&15][k=quad*8+j],
// B[k=quad*8+j][n=lane&15], C/D col=lane&15,row=quad*4+reg.
// Per kv-iteration each thread computes the exact 16 mask bits it consumes
// ((r,nt) pairs) — pure VALU, no memory dependence, scheduled into the idle
// issue slots of the MFMA/latency phases.
// LDS: 16384*3 + 9216 = 58368 B -> 2 blocks/CU.
// ---------------------------------------------------------------------------
__global__ __launch_bounds__(256) void attn_kernel(
    const float* __restrict__ x1,
    float*       __restrict__ out)
{
  __shared__ __align__(16) _Float16 Ksh[64 * 128];
  __shared__ __align__(16) _Float16 Ksl[64 * 128];
  __shared__ __align__(16) _Float16 Vt[128 * 64];
  __shared__ __align__(16) _Float16 Ps[64 * 72];

  const int tid = threadIdx.x;
  const int blk = blockIdx.x;
  // XCD swizzle: batches {2x,2x+1} pin to XCD x
  const int b     = ((blk & 7) << 1) | ((blk >> 3) & 1);
  const int qt    = blk >> 4;
  const int qbase = qt * 64;
  const int lane = tid & 63, w = tid >> 6;
  const int quad = lane >> 4, c16 = lane & 15;

  // ---- Q fragments from global fp32, hi/lo f16 split in registers ----
  half8 qh[4], ql[4];
  {
    const float* qrow = x1 + ((size_t)(b * NQ + qbase + w * 16 + c16)) * DH;
    #pragma unroll
    for (int c = 0; c < 4; ++c) {
      #pragma unroll
      for (int j = 0; j < 8; ++j) {
        float v = qrow[c * 32 + quad * 8 + j];
        _Float16 h = (_Float16)v;
        qh[c][j] = h;
        ql[c][j] = (_Float16)(v - (float)h);
      }
    }
  }

  floatx4 acc[8];
  #pragma unroll
  for (int i = 0; i < 8; ++i) acc[i] = (floatx4){0.f, 0.f, 0.f, 0.f};
  float m_i[4] = {-INFINITY, -INFINITY, -INFINITY, -INFINITY};
  float l_i[4] = {0.f, 0.f, 0.f, 0.f};

  const size_t kofs = (size_t)b * NK * DH;   // x2h / x2l base
  const size_t tofs = (size_t)b * DH * NK;   // x2t base

  // threefry counter base for this thread's q-rows: (b*NQ + q)*NK + c16
  const unsigned rowc0 = (unsigned)(b * NQ + qbase + w * 16 + quad * 4) * (unsigned)NK
                       + (unsigned)c16;

  for (int kv = 0; kv < NK; kv += 64) {
    __syncthreads();   // prev iteration's Ks/Vt reads complete

    // ---- staging: pure b128 copies, XOR-swizzled chunk layout ----
    #pragma unroll
    for (int t = 0; t < 4; ++t) {
      int idx = tid + t * 256;               // 0..1023
      int r  = idx >> 4, c8 = idx & 15;      // K: row 0..63, d-chunk 0..15
      size_t go = kofs + (size_t)(kv + r) * DH + c8 * 8;
      uint4 vh = *(const uint4*)&g_x2h[go];
      uint4 vl = *(const uint4*)&g_x2l[go];
      int ka = r * 128 + ((c8 ^ (r & 15)) << 3);
      *(uint4*)&Ksh[ka] = vh;
      *(uint4*)&Ksl[ka] = vl;
      int d  = idx >> 3, ch = idx & 7;       // Vt: d 0..127, kv-chunk 0..7
      uint4 vt = *(const uint4*)&g_x2t[tofs + (size_t)d * NK + kv + ch * 8];
      *(uint4*)&Vt[d * 64 + ((ch ^ (d & 7)) << 3)] = vt;
    }
    __syncthreads();

    // ---- fused dropout mask: 16 threefry evals (pure VALU, no deps) ----
    // bit (r*4+nt) = keep for element (q = base+r, k = kv + nt*16 + c16)
    unsigned keepbits = 0u;
    {
      const unsigned ibase = rowc0 + (unsigned)kv;
      #pragma unroll
      for (int r = 0; r < 4; ++r) {
        #pragma unroll
        for (int nt = 0; nt < 4; ++nt) {
          keepbits |= tf_keep(ibase + (unsigned)(r * NK + nt * 16))
                      << (r * 4 + nt);
        }
      }
    }

    // ---- S = Q.K^T, 3-term hi/lo ----
    floatx4 S[4];
    #pragma unroll
    for (int nt = 0; nt < 4; ++nt) {
      S[nt] = (floatx4){0.f, 0.f, 0.f, 0.f};
      int row = nt * 16 + c16;
      int rbase = row * 128, rx = row & 15;
      #pragma unroll
      for (int c = 0; c < 4; ++c) {
        int addr = rbase + (((c * 4 + quad) ^ rx) << 3);
        half8 kh = *(const half8*)&Ksh[addr];
        half8 kl = *(const half8*)&Ksl[addr];
        S[nt] = __builtin_amdgcn_mfma_f32_16x16x32_f16(qh[c], kh, S[nt], 0, 0, 0);
        S[nt] = __builtin_amdgcn_mfma_f32_16x16x32_f16(ql[c], kh, S[nt], 0, 0, 0);
        S[nt] = __builtin_amdgcn_mfma_f32_16x16x32_f16(qh[c], kl, S[nt], 0, 0, 0);
      }
    }
    #pragma unroll
    for (int nt = 0; nt < 4; ++nt)
      #pragma unroll
      for (int r = 0; r < 4; ++r) S[nt][r] *= SCALEF;

    // ---- online softmax (row quad*4+r lives in the quad's 16 lanes) ----
    float mx[4];
    #pragma unroll
    for (int r = 0; r < 4; ++r)
      mx[r] = fmaxf(fmaxf(S[0][r], S[1][r]), fmaxf(S[2][r], S[3][r]));
    #pragma unroll
    for (int off = 1; off < 16; off <<= 1)
      #pragma unroll
      for (int r = 0; r < 4; ++r)
        mx[r] = fmaxf(mx[r], __shfl_xor(mx[r], off));

    float alpha[4];
    #pragma unroll
    for (int r = 0; r < 4; ++r) {
      float mo = m_i[r];
      float mn = fmaxf(mo, mx[r]);
      m_i[r] = mn;
      alpha[r] = __expf(mo - mn);          // first iter: exp(-inf) = 0
      l_i[r] *= alpha[r];
    }
    float p[4][4];
    #pragma unroll
    for (int nt = 0; nt < 4; ++nt)
      #pragma unroll
      for (int r = 0; r < 4; ++r)
        p[nt][r] = __expf(S[nt][r] - m_i[r]);
    #pragma unroll
    for (int r = 0; r < 4; ++r)
      l_i[r] += (p[0][r] + p[1][r]) + (p[2][r] + p[3][r]);  // UNMASKED sum
    #pragma unroll
    for (int dt = 0; dt < 8; ++dt)
      #pragma unroll
      for (int r = 0; r < 4; ++r) acc[dt][r] *= alpha[r];

    // ---- dropout gate + P -> LDS (C-layout -> A-layout); wave-private ----
    #pragma unroll
    for (int r = 0; r < 4; ++r) {
      #pragma unroll
      for (int nt = 0; nt < 4; ++nt) {
        float pv = ((keepbits >> (r * 4 + nt)) & 1u) ? p[nt][r] : 0.0f;
        Ps[(w * 16 + quad * 4 + r) * 72 + nt * 16 + c16] = (_Float16)pv;
      }
    }
    // no barrier: Ps rows are wave-private (verified passing in R9)

    // ---- O += P.V (Vt reads undo the XOR swizzle) ----
    #pragma unroll
    for (int kc = 0; kc < 2; ++kc) {
      half8 af = *(const half8*)&Ps[(w * 16 + c16) * 72 + kc * 32 + quad * 8];
      #pragma unroll
      for (int dt = 0; dt < 8; ++dt) {
        int d = dt * 16 + c16;
        half8 bf = *(const half8*)&Vt[d * 64 + ((((kc << 2) + quad) ^ (d & 7)) << 3)];
        acc[dt] = __builtin_amdgcn_mfma_f32_16x16x32_f16(af, bf, acc[dt], 0, 0, 0);
      }
    }
  }

  // ---- finalize: cross-lane l sum, normalize by (l * keep), store fp32 ----
  #pragma unroll
  for (int off = 1; off < 16; off <<= 1)
    #pragma unroll
    for (int r = 0; r < 4; ++r)
      l_i[r] += __shfl_xor(l_i[r], off);
  float inv[4];
  #pragma unroll
  for (int r = 0; r < 4; ++r) inv[r] = 1.0f / (KEEPF * l_i[r]);

  #pragma unroll
  for (int dt = 0; dt < 8; ++dt)
    #pragma unroll
    for (int r = 0; r < 4; ++r) {
      int q = qbase + w * 16 + quad * 4 + r;
      out[((size_t)(b * NQ + q)) * DH + dt * 16 + c16] = acc[dt][r] * inv[r];
    }
}

// ---------------------------------------------------------------------------
// launch: light prep (x2 conversion/transpose only), then fused attention.
// d_ws unused.
// ---------------------------------------------------------------------------
extern "C" void kernel_launch(void* const* d_in, const int* in_sizes, int n_in,
                              void* d_out, int out_size, void* d_ws, size_t ws_size,
                              hipStream_t stream) {
  const float* x1 = (const float*)d_in[0];
  const float* x2 = (const float*)d_in[1];
  float* out = (float*)d_out;

  prep_conv<<<3072, 256, 0, stream>>>(x2);
  attn_kernel<<<512, 256, 0, stream>>>(x1, out);
}